// Round 5
// baseline (2925.579 us; speedup 1.0000x reference)
//
#include <hip/hip_runtime.h>
#include <hip/hip_bf16.h>

// VAE_RNN: B=4096, T=200, D=128, L=64, H=128, CIN=2L+D=256
// Persistent-block RNN, 512 blocks x 512 threads (8 waves), 8 batch rows per
// block -> TWO co-resident blocks per CU (4 waves/SIMD). Independent per-block
// barrier schedules overlap: one block's MFMA phase hides the other's
// LDS/barrier latency (R4 showed the kernel is latency-bound, TLP-controlled).
// MFMA tiles keep 16 rows; rows 8..15 are zero-initialized garbage rows,
// row-confined (batch rows never mix in any GEMM), never stored out.
// Weights register-resident as bf16 MFMA fragments; mfma(W_frag, act_frag, acc)
// computes (W^T @ h^T): lane holds 4 consecutive features of one batch row.
// Barriers are lgkmcnt-only: x(t+1) global prefetch stays in flight across
// all phase barriers, waited only at its use in phase D.

#define NB 4096
#define NT 200
#define ND 128
#define NR 8            // batch rows per block

typedef __bf16 bf16;
typedef __attribute__((ext_vector_type(8))) __bf16 bf16x8;
typedef __attribute__((ext_vector_type(4))) __bf16 bf16x4;
typedef __attribute__((ext_vector_type(2))) __bf16 bf16x2;
typedef __attribute__((ext_vector_type(4))) float f32x4;

#define BAR() asm volatile("s_waitcnt lgkmcnt(0)\n\ts_barrier" ::: "memory")

__device__ __forceinline__ f32x4 mfma16(bf16x8 a, bf16x8 b, f32x4 c){
    return __builtin_amdgcn_mfma_f32_16x16x32_bf16(a, b, c, 0, 0, 0);
}
// inf-safe, branch-free
__device__ __forceinline__ float fast_tanh(float x){
    float e = __expf(2.f * x);
    return 1.f - 2.f * __builtin_amdgcn_rcpf(e + 1.f);
}
__device__ __forceinline__ float fast_sigmoid(float x){
    return __builtin_amdgcn_rcpf(1.f + __expf(-x));
}
__device__ __forceinline__ bf16x4 tanh4_bf16(f32x4 a, float4 b){
    bf16x4 o;
    o[0] = (bf16)fast_tanh(a[0] + b.x);
    o[1] = (bf16)fast_tanh(a[1] + b.y);
    o[2] = (bf16)fast_tanh(a[2] + b.z);
    o[3] = (bf16)fast_tanh(a[3] + b.w);
    return o;
}

__global__ __launch_bounds__(512, 4)
void vae_rnn(const float* __restrict__ data,
             const float* __restrict__ ug_w1, const float* __restrict__ ug_b1,
             const float* __restrict__ ug_w2, const float* __restrict__ ug_b2,
             const float* __restrict__ rg_w1, const float* __restrict__ rg_b1,
             const float* __restrict__ rg_w2, const float* __restrict__ rg_b2,
             const float* __restrict__ ns_w1, const float* __restrict__ ns_b1,
             const float* __restrict__ ns_w2, const float* __restrict__ ns_b2,
             float* __restrict__ out)
{
    // bf16 tiles, XOR-swizzled: byte = row*stride + ((col*2) ^ ((row&7)<<4))
    __shared__ __align__(16) char h_lds [16 * 512];   // 16 x 256 bf16: [y|s|x] / [y*r|s*r|x]
    __shared__ __align__(16) char t_lds [16 * 512];   // 16 x 256 bf16: tanh(l1) of [ug|rg]
    __shared__ __align__(16) char tn_lds[16 * 256];   // 16 x 128 bf16: tanh(l1) of ns
    __shared__ float u_lds [16][68];                  // u gate fp32
    __shared__ float ys_lds[16][132];                 // y (0..63), s (64..127) fp32

    const int tid  = threadIdx.x;
    const int wave = tid >> 6;
    const int lane = tid & 63;
    const int lq   = lane >> 4;
    const int lc   = lane & 15;          // batch row within tile (rows >= NR: garbage lanes)
    const int sw   = (lc & 7) << 4;      // read swizzle for row lc
    const int row0 = blockIdx.x * NR;

    // ---------------- persistent weight fragments (bf16, registers) -------------
    bf16x8 wA[16]; float4 bA[2];
    #pragma unroll
    for (int j = 0; j < 2; ++j){
        int c = wave*32 + j*16 + lc;
        const float* W  = (c < 128) ? ug_w1 : rg_w1;
        int n = c & 127;
        int fb = (wave*32 + j*16 + lq*4) & 127;
        const float* bb = ((wave*32 + j*16) < 128) ? ug_b1 : rg_b1;
        bA[j] = make_float4(bb[fb], bb[fb+1], bb[fb+2], bb[fb+3]);
        #pragma unroll
        for (int kt = 0; kt < 8; ++kt){
            int k0 = kt*32 + lq*8;
            bf16x8 f;
            #pragma unroll
            for (int e = 0; e < 8; ++e) f[e] = (bf16)W[(k0 + e)*128 + n];
            wA[kt*2 + j] = f;
        }
    }
    bf16x8 wB[4]; float4 bB;
    {
        const float* W  = (wave < 4) ? ug_w2 : rg_w2;
        const float* bb = (wave < 4) ? ug_b2 : rg_b2;
        int n  = (wave & 3)*16 + lc;
        int fb = (wave & 3)*16 + lq*4;
        bB = make_float4(bb[fb], bb[fb+1], bb[fb+2], bb[fb+3]);
        #pragma unroll
        for (int kt = 0; kt < 4; ++kt){
            int k0 = kt*32 + lq*8;
            bf16x8 f;
            #pragma unroll
            for (int e = 0; e < 8; ++e) f[e] = (bf16)W[(k0 + e)*64 + n];
            wB[kt] = f;
        }
    }
    bf16x8 wC[8]; float4 bC;
    {
        int n  = wave*16 + lc;
        int fb = wave*16 + lq*4;
        bC = make_float4(ns_b1[fb], ns_b1[fb+1], ns_b1[fb+2], ns_b1[fb+3]);
        #pragma unroll
        for (int kt = 0; kt < 8; ++kt){
            int k0 = kt*32 + lq*8;
            bf16x8 f;
            #pragma unroll
            for (int e = 0; e < 8; ++e) f[e] = (bf16)ns_w1[(k0 + e)*128 + n];
            wC[kt] = f;
        }
    }
    bf16x8 wD[4]; float4 bD;
    {
        int n  = wave*16 + lc;
        int fb = wave*16 + lq*4;
        bD = make_float4(ns_b2[fb], ns_b2[fb+1], ns_b2[fb+2], ns_b2[fb+3]);
        #pragma unroll
        for (int kt = 0; kt < 4; ++kt){
            int k0 = kt*32 + lq*8;
            bf16x8 f;
            #pragma unroll
            for (int e = 0; e < 8; ++e) f[e] = (bf16)ns_w2[(k0 + e)*128 + n];
            wD[kt] = f;
        }
    }

    // init: zero ys and ALL of h (incl. garbage rows 8..15), then x(0) rows 0..7
    for (int i = tid; i < 16*132; i += 512) (&ys_lds[0][0])[i] = 0.f;
    {
        bf16x8 z = {};
        *(bf16x8*)(h_lds + tid*16) = z;       // 512 threads x 16B = 8192B = whole tile
    }
    const int xr  = tid >> 6;             // 0..7 (= wave)
    const int xc2 = (lane) << 1;          // 0,2,...,126
    const int swx = (xr & 7) << 4;
    const float* xbase = data + (size_t)(row0 + xr) * (NT * ND) + xc2;
    BAR();
    {
        float2 x0 = *(const float2*)xbase;
        bf16x2 xb = { (bf16)x0.x, (bf16)x0.y };
        *(bf16x2*)(h_lds + xr*512 + (((128+xc2)*2) ^ swx)) = xb;
    }
    BAR();

    #pragma unroll 1
    for (int t = 0; t < NT; ++t){
        // prefetch x(t+1): stays in flight through A/B/C (lgkm-only barriers)
        int tn1 = (t + 1 < NT) ? (t + 1) : (NT - 1);
        float2 xnext = *(const float2*)(xbase + tn1*ND);

        bf16x8 xf[4];   // x-fragments cached A -> C

        // ---- Phase A: t = tanh(h @ [ug_w1|rg_w1] + b1), transposed-out ----
        {
            f32x4 acc[2][2] = {};
            #pragma unroll
            for (int kt = 0; kt < 8; ++kt){
                bf16x8 av = *(const bf16x8*)(h_lds + lc*512 + ((kt*64 + lq*16) ^ sw));
                if (kt >= 4) xf[kt-4] = av;
                acc[0][kt&1] = mfma16(wA[kt*2+0], av, acc[0][kt&1]);
                acc[1][kt&1] = mfma16(wA[kt*2+1], av, acc[1][kt&1]);
            }
            #pragma unroll
            for (int j = 0; j < 2; ++j){
                f32x4 a = acc[j][0] + acc[j][1];
                int f0 = wave*32 + j*16 + lq*4;
                *(bf16x4*)(t_lds + lc*512 + ((f0*2) ^ sw)) = tanh4_bf16(a, bA[j]);
            }
        }
        BAR();

        // ---- Phase B: u|r = sigmoid(t_half @ w2 + b2); r-waves write hc ----
        {
            float4 y4 = {}, s4 = {};
            int f0 = (wave & 3)*16 + lq*4;
            if (wave >= 4){
                y4 = *(const float4*)&ys_lds[lc][f0];
                s4 = *(const float4*)&ys_lds[lc][64 + f0];
            }
            f32x4 acc0 = {}, acc1 = {};
            const int off = (wave < 4) ? 0 : 256;
            #pragma unroll
            for (int kt = 0; kt < 4; ++kt){
                bf16x8 av = *(const bf16x8*)(t_lds + lc*512 + ((off + kt*64 + lq*16) ^ sw));
                if (kt & 1) acc1 = mfma16(wB[kt], av, acc1);
                else        acc0 = mfma16(wB[kt], av, acc0);
            }
            f32x4 acc = acc0 + acc1;
            float g0 = fast_sigmoid(acc[0] + bB.x);
            float g1 = fast_sigmoid(acc[1] + bB.y);
            float g2 = fast_sigmoid(acc[2] + bB.z);
            float g3 = fast_sigmoid(acc[3] + bB.w);
            if (wave < 4){
                *(float4*)&u_lds[lc][f0] = make_float4(g0, g1, g2, g3);
            } else {
                bf16x4 hy = { (bf16)(y4.x*g0), (bf16)(y4.y*g1), (bf16)(y4.z*g2), (bf16)(y4.w*g3) };
                bf16x4 hs = { (bf16)(s4.x*g0), (bf16)(s4.y*g1), (bf16)(s4.z*g2), (bf16)(s4.w*g3) };
                *(bf16x4*)(h_lds + lc*512 + ((f0*2)      ^ sw)) = hy;
                *(bf16x4*)(h_lds + lc*512 + (((64+f0)*2) ^ sw)) = hs;
            }
        }
        BAR();

        // ---- Phase C: tn = tanh(hc @ ns_w1 + b); also pre-read u/ys for D ----
        float4 u4, o4;
        {
            int fd = (wave & 3)*16 + lq*4;
            int sc = (wave >= 4) ? 64 : 0;
            u4 = *(const float4*)&u_lds[lc][fd];
            o4 = *(const float4*)&ys_lds[lc][sc + fd];

            f32x4 acc[2] = {};
            #pragma unroll
            for (int kt = 0; kt < 4; ++kt){
                bf16x8 av = *(const bf16x8*)(h_lds + lc*512 + ((kt*64 + lq*16) ^ sw));
                acc[kt&1] = mfma16(wC[kt], av, acc[kt&1]);
            }
            #pragma unroll
            for (int kt = 4; kt < 8; ++kt)
                acc[kt&1] = mfma16(wC[kt], xf[kt-4], acc[kt&1]);   // cached x-frags
            f32x4 a = acc[0] + acc[1];
            int f0 = wave*16 + lq*4;
            *(bf16x4*)(tn_lds + lc*256 + ((f0*2) ^ sw)) = tanh4_bf16(a, bC);
        }
        BAR();

        // ---- Phase D: ns = tn @ ns_w2 + b; EMA update; refresh h for t+1 ----
        {
            f32x4 acc0 = {}, acc1 = {};
            #pragma unroll
            for (int kt = 0; kt < 4; ++kt){
                bf16x8 av = *(const bf16x8*)(tn_lds + lc*256 + ((kt*64 + lq*16) ^ sw));
                if (kt & 1) acc1 = mfma16(wD[kt], av, acc1);
                else        acc0 = mfma16(wD[kt], av, acc0);
            }
            f32x4 acc = acc0 + acc1;
            int f0 = (wave & 3)*16 + lq*4;
            int sc = (wave >= 4) ? 64 : 0;
            float v0 = acc[0] + bD.x, v1 = acc[1] + bD.y;
            float v2 = acc[2] + bD.z, v3 = acc[3] + bD.w;
            if (wave >= 4){ v0 = fabsf(v0); v1 = fabsf(v1); v2 = fabsf(v2); v3 = fabsf(v3); }
            float n0 = fmaf(u4.x, o4.x - v0, v0);
            float n1 = fmaf(u4.y, o4.y - v1, v1);
            float n2 = fmaf(u4.z, o4.z - v2, v2);
            float n3 = fmaf(u4.w, o4.w - v3, v3);
            *(float4*)&ys_lds[lc][sc + f0] = make_float4(n0, n1, n2, n3);
            bf16x4 hn = { (bf16)n0, (bf16)n1, (bf16)n2, (bf16)n3 };
            *(bf16x4*)(h_lds + lc*512 + (((sc + f0)*2) ^ sw)) = hn;
            // refresh x columns (rows 0..7) with x(t+1)
            bf16x2 xb = { (bf16)xnext.x, (bf16)xnext.y };
            *(bf16x2*)(h_lds + xr*512 + (((128+xc2)*2) ^ swx)) = xb;
        }
        BAR();
    }

    // output: yT (4096x64) then sT (4096x64), fp32 — rows 0..7 only
    {
        int orow = tid >> 6;            // 0..7
        int ocol = (tid & 63) << 1;     // 0..126
        float2 v = *(const float2*)&ys_lds[orow][ocol];
        size_t gr = (size_t)(row0 + orow);
        if (ocol < 64) *(float2*)&out[gr*64 + ocol] = v;
        else           *(float2*)&out[(size_t)NB*64 + gr*64 + (ocol - 64)] = v;
    }
}

extern "C" void kernel_launch(void* const* d_in, const int* in_sizes, int n_in,
                              void* d_out, int out_size, void* d_ws, size_t ws_size,
                              hipStream_t stream) {
    const float* data  = (const float*)d_in[0];
    // d_in[1] = time_steps — unused by the reference computation
    const float* ug_w1 = (const float*)d_in[2];
    const float* ug_b1 = (const float*)d_in[3];
    const float* ug_w2 = (const float*)d_in[4];
    const float* ug_b2 = (const float*)d_in[5];
    const float* rg_w1 = (const float*)d_in[6];
    const float* rg_b1 = (const float*)d_in[7];
    const float* rg_w2 = (const float*)d_in[8];
    const float* rg_b2 = (const float*)d_in[9];
    const float* ns_w1 = (const float*)d_in[10];
    const float* ns_b1 = (const float*)d_in[11];
    const float* ns_w2 = (const float*)d_in[12];
    const float* ns_b2 = (const float*)d_in[13];

    hipLaunchKernelGGL(vae_rnn, dim3(NB/NR), dim3(512), 0, stream,
                       data, ug_w1, ug_b1, ug_w2, ug_b2,
                       rg_w1, rg_b1, rg_w2, rg_b2,
                       ns_w1, ns_b1, ns_w2, ns_b2,
                       (float*)d_out);
}

// Round 6
// 359.869 us; speedup vs baseline: 8.1296x; 8.1296x over previous
//
#include <hip/hip_runtime.h>
#include <hip/hip_bf16.h>

// VAE_RNN: B=4096, T=200, D=128, L=64, H=128, CIN=2L+D=256
// Persistent-block RNN, 256 blocks x 512 threads, 16 rows/block, 200 steps.
// WAVE-GROUP PHASE SPECIALIZATION: waves 0-3 (G0) own GEMMs A,B; waves 4-7
// (G1) own GEMMs C,D. Each GEMM runs on 4 fat waves -> per-phase LDS read
// burst halves vs 8-wave split (the R3 limiter: 64 serialized ds_read_b128
// per phase). Parked group waits at the barrier for free.
//   I1: G0: A = tanh(h@W1)         || G1: C's x-part (x(t) stable)
//   I2: G0: B = sigmoid(t@W2), hc  || G1: idle
//   I3: G1: C's hc-part -> tn      || G0: idle
//   I4: G1: D = tn@ns_w2, EMA      || G0: x(t+1) refresh
// Weights register-resident; mfma(W_frag, act_frag, acc) computes W^T@h^T so
// each lane holds 4 consecutive features of one batch row. Biases in acc-init.
// D-waves carry old y/s state in REGISTERS (no ys re-read for EMA).
// Linear LDS rows, stride 528B/272B (132/68 dwords = 4 mod 32 -> ~2-way only).
// lgkmcnt-only barriers keep the x(t+1) global prefetch in flight all step.

#define NB 4096
#define NT 200
#define ND 128
#define HS 528      // h/t row stride (bytes)
#define TS 272      // tn row stride (bytes)

typedef __bf16 bf16;
typedef __attribute__((ext_vector_type(8))) __bf16 bf16x8;
typedef __attribute__((ext_vector_type(4))) __bf16 bf16x4;
typedef __attribute__((ext_vector_type(4))) float f32x4;

#define BAR() asm volatile("s_waitcnt lgkmcnt(0)\n\ts_barrier" ::: "memory")

__device__ __forceinline__ f32x4 mfma16(bf16x8 a, bf16x8 b, f32x4 c){
    return __builtin_amdgcn_mfma_f32_16x16x32_bf16(a, b, c, 0, 0, 0);
}
// inf-safe, branch-free
__device__ __forceinline__ float fast_tanh(float x){
    float e = __expf(2.f * x);
    return 1.f - 2.f * __builtin_amdgcn_rcpf(e + 1.f);
}
__device__ __forceinline__ float fast_sigmoid(float x){
    return __builtin_amdgcn_rcpf(1.f + __expf(-x));
}
__device__ __forceinline__ bf16x4 tanh4(f32x4 a){
    bf16x4 o;
    o[0] = (bf16)fast_tanh(a[0]);
    o[1] = (bf16)fast_tanh(a[1]);
    o[2] = (bf16)fast_tanh(a[2]);
    o[3] = (bf16)fast_tanh(a[3]);
    return o;
}
__device__ __forceinline__ f32x4 bias4(const float* b, int f){
    f32x4 r; r[0] = b[f]; r[1] = b[f+1]; r[2] = b[f+2]; r[3] = b[f+3]; return r;
}

__global__ __launch_bounds__(512, 2)
void vae_rnn(const float* __restrict__ data,
             const float* __restrict__ ug_w1, const float* __restrict__ ug_b1,
             const float* __restrict__ ug_w2, const float* __restrict__ ug_b2,
             const float* __restrict__ rg_w1, const float* __restrict__ rg_b1,
             const float* __restrict__ rg_w2, const float* __restrict__ rg_b2,
             const float* __restrict__ ns_w1, const float* __restrict__ ns_b1,
             const float* __restrict__ ns_w2, const float* __restrict__ ns_b2,
             float* __restrict__ out)
{
    __shared__ __align__(16) char h_lds [16 * HS];   // 16 x 256 bf16 [y|s|x] (+pad)
    __shared__ __align__(16) char t_lds [16 * HS];   // 16 x 256 bf16 tanh(l1) [ug|rg]
    __shared__ __align__(16) char tn_lds[16 * TS];   // 16 x 128 bf16 tanh(l1) ns
    __shared__ float u_lds [16][68];                 // u gate fp32
    __shared__ float ys_lds[16][132];                // y (0..63), s (64..127) fp32

    const int tid  = threadIdx.x;
    const int wave = tid >> 6;
    const int lane = tid & 63;
    const int lq   = lane >> 4;
    const int lc   = lane & 15;          // batch row within tile
    const int row0 = blockIdx.x * 16;

    // x loader mapping (threads 0..255): row pr, 8-float chunk pc
    const int pr = tid >> 4;
    const int pc = tid & 15;
    const float* xsrc = data + (size_t)(row0 + pr) * (NT * ND) + pc * 8;

    // ---------------- prologue: ys=0, h=[0|0|x(0)] ----------------
    for (int i = tid; i < 16*132; i += 512) (&ys_lds[0][0])[i] = 0.f;
    if (tid < 256){
        bf16x8 z = {};
        *(bf16x8*)(h_lds + pr*HS + pc*16) = z;          // y,s cols
        float4 a0 = *(const float4*)xsrc;
        float4 a1 = *(const float4*)(xsrc + 4);
        bf16x8 xv = { (bf16)a0.x,(bf16)a0.y,(bf16)a0.z,(bf16)a0.w,
                      (bf16)a1.x,(bf16)a1.y,(bf16)a1.z,(bf16)a1.w };
        *(bf16x8*)(h_lds + pr*HS + 256 + pc*16) = xv;   // x cols
    }
    __syncthreads();

    if (wave < 4){
        // ======================= G0: GEMMs A and B =======================
        const int g  = wave;
        const bool UROLE = (g < 2);          // B-phase role: u-gate vs r-gate
        const float* W1 = UROLE ? ug_w1 : rg_w1;
        const float* B1 = UROLE ? ug_b1 : rg_b1;
        const float* W2 = UROLE ? ug_w2 : rg_w2;
        const float* B2 = UROLE ? ug_b2 : rg_b2;
        const int f1 = (g & 1) * 64;         // A feats within its W1 half
        const int f2 = (g & 1) * 32;         // B gate-output base

        bf16x8 wA[32]; f32x4 bA[4];
        #pragma unroll
        for (int j = 0; j < 4; ++j){
            int n = f1 + j*16 + lc;
            bA[j] = bias4(B1, f1 + j*16 + lq*4);
            #pragma unroll
            for (int kt = 0; kt < 8; ++kt){
                bf16x8 f;
                #pragma unroll
                for (int e = 0; e < 8; ++e) f[e] = (bf16)W1[(kt*32 + lq*8 + e)*128 + n];
                wA[kt*4 + j] = f;
            }
        }
        bf16x8 wB[8]; f32x4 bB[2];
        #pragma unroll
        for (int j = 0; j < 2; ++j){
            int n = f2 + j*16 + lc;
            bB[j] = bias4(B2, f2 + j*16 + lq*4);
            #pragma unroll
            for (int kt = 0; kt < 4; ++kt){
                bf16x8 f;
                #pragma unroll
                for (int e = 0; e < 8; ++e) f[e] = (bf16)W2[(kt*32 + lq*8 + e)*64 + n];
                wB[kt*2 + j] = f;
            }
        }

        const char* h_rd  = h_lds + lc*HS + lq*16;                 // + kt*64
        char*       t_wr  = t_lds + lc*HS + g*128 + lq*8;          // + j*32
        const char* t_rd  = t_lds + lc*HS + lq*16 + (UROLE ? 0 : 256);
        char*       hc_wr = h_lds + lc*HS + f2*2 + lq*8;           // y*r; +128 s*r
        char*       x_wr  = h_lds + pr*HS + 256 + pc*16;
        const int   rc    = f2 + lq*4;

        #pragma unroll 1
        for (int t = 0; t < NT; ++t){
            // x(t+1) prefetch: in flight across all lgkm-only barriers
            int tn1 = (t + 1 < NT) ? (t + 1) : (NT - 1);
            float4 xa = *(const float4*)(xsrc + (size_t)tn1*ND);
            float4 xb = *(const float4*)(xsrc + (size_t)tn1*ND + 4);

            // ---- I1: A = tanh(h @ W1 + b1) : 8 reads, 32 MFMA, 4 chains ----
            f32x4 a0 = bA[0], a1 = bA[1], a2 = bA[2], a3 = bA[3];
            #pragma unroll
            for (int kt = 0; kt < 8; ++kt){
                bf16x8 hv = *(const bf16x8*)(h_rd + kt*64);
                a0 = mfma16(wA[kt*4+0], hv, a0);
                a1 = mfma16(wA[kt*4+1], hv, a1);
                a2 = mfma16(wA[kt*4+2], hv, a2);
                a3 = mfma16(wA[kt*4+3], hv, a3);
            }
            *(bf16x4*)(t_wr +  0) = tanh4(a0);
            *(bf16x4*)(t_wr + 32) = tanh4(a1);
            *(bf16x4*)(t_wr + 64) = tanh4(a2);
            *(bf16x4*)(t_wr + 96) = tanh4(a3);
            BAR();

            // ---- I2: B = sigmoid(t_half @ W2 + b2); r-waves write hc ----
            float4 y0, y1, s0, s1;
            if (!UROLE){
                y0 = *(const float4*)&ys_lds[lc][rc];
                y1 = *(const float4*)&ys_lds[lc][rc + 16];
                s0 = *(const float4*)&ys_lds[lc][64 + rc];
                s1 = *(const float4*)&ys_lds[lc][80 + rc];
            }
            f32x4 b0 = bB[0], b1 = bB[1];
            #pragma unroll
            for (int kt = 0; kt < 4; ++kt){
                bf16x8 tv = *(const bf16x8*)(t_rd + kt*64);
                b0 = mfma16(wB[kt*2+0], tv, b0);
                b1 = mfma16(wB[kt*2+1], tv, b1);
            }
            float g00 = fast_sigmoid(b0[0]), g01 = fast_sigmoid(b0[1]);
            float g02 = fast_sigmoid(b0[2]), g03 = fast_sigmoid(b0[3]);
            float g10 = fast_sigmoid(b1[0]), g11 = fast_sigmoid(b1[1]);
            float g12 = fast_sigmoid(b1[2]), g13 = fast_sigmoid(b1[3]);
            if (UROLE){
                *(float4*)&u_lds[lc][rc]      = make_float4(g00, g01, g02, g03);
                *(float4*)&u_lds[lc][rc + 16] = make_float4(g10, g11, g12, g13);
            } else {
                bf16x4 hy0 = { (bf16)(y0.x*g00), (bf16)(y0.y*g01), (bf16)(y0.z*g02), (bf16)(y0.w*g03) };
                bf16x4 hy1 = { (bf16)(y1.x*g10), (bf16)(y1.y*g11), (bf16)(y1.z*g12), (bf16)(y1.w*g13) };
                bf16x4 hs0 = { (bf16)(s0.x*g00), (bf16)(s0.y*g01), (bf16)(s0.z*g02), (bf16)(s0.w*g03) };
                bf16x4 hs1 = { (bf16)(s1.x*g10), (bf16)(s1.y*g11), (bf16)(s1.z*g12), (bf16)(s1.w*g13) };
                *(bf16x4*)(hc_wr +   0) = hy0;
                *(bf16x4*)(hc_wr +  32) = hy1;
                *(bf16x4*)(hc_wr + 128) = hs0;
                *(bf16x4*)(hc_wr + 160) = hs1;
            }
            BAR();

            // ---- I3: idle (G1 computes C's hc-part) ----
            BAR();

            // ---- I4: refresh x columns with x(t+1) ----
            {
                bf16x8 xv = { (bf16)xa.x,(bf16)xa.y,(bf16)xa.z,(bf16)xa.w,
                              (bf16)xb.x,(bf16)xb.y,(bf16)xb.z,(bf16)xb.w };
                *(bf16x8*)x_wr = xv;
            }
            BAR();
        }
    } else {
        // ======================= G1: GEMMs C and D =======================
        const int g   = wave - 4;
        const bool STD = (g >= 2);           // D-phase role: std vs mean

        bf16x8 wC[16]; f32x4 bC[2];
        #pragma unroll
        for (int j = 0; j < 2; ++j){
            int n = g*32 + j*16 + lc;
            bC[j] = bias4(ns_b1, g*32 + j*16 + lq*4);
            #pragma unroll
            for (int kt = 0; kt < 8; ++kt){
                bf16x8 f;
                #pragma unroll
                for (int e = 0; e < 8; ++e) f[e] = (bf16)ns_w1[(kt*32 + lq*8 + e)*128 + n];
                wC[kt*2 + j] = f;
            }
        }
        bf16x8 wD[8]; f32x4 bD[2];
        #pragma unroll
        for (int j = 0; j < 2; ++j){
            int n = g*32 + j*16 + lc;
            bD[j] = bias4(ns_b2, g*32 + j*16 + lq*4);
            #pragma unroll
            for (int kt = 0; kt < 4; ++kt){
                bf16x8 f;
                #pragma unroll
                for (int e = 0; e < 8; ++e) f[e] = (bf16)ns_w2[(kt*32 + lq*8 + e)*128 + n];
                wD[kt*2 + j] = f;
            }
        }

        const char* x_rd  = h_lds  + lc*HS + 256 + lq*16;   // x cols, + kt*64
        const char* hc_rd = h_lds  + lc*HS + lq*16;         // hc cols, + kt*64
        char*       tn_wr = tn_lds + lc*TS + g*64 + lq*8;   // + j*32
        const char* tn_rd = tn_lds + lc*TS + lq*16;         // + kt*64
        char*       hy_wr = h_lds  + lc*HS + g*64 + lq*8;   // new y/s bf16, + j*32
        const int   fD = g*32 + lq*4;                       // ys_lds col base
        const int   uC = (g & 1)*32 + lq*4;                 // u_lds col base

        f32x4 old0 = {0.f,0.f,0.f,0.f}, old1 = {0.f,0.f,0.f,0.f};  // carried state

        #pragma unroll 1
        for (int t = 0; t < NT; ++t){
            // ---- I1: C's x-part (x(t) stable; runs under G0's A) ----
            f32x4 c0 = bC[0], c1 = bC[1];
            #pragma unroll
            for (int kt = 0; kt < 4; ++kt){
                bf16x8 xv = *(const bf16x8*)(x_rd + kt*64);
                c0 = mfma16(wC[(kt+4)*2+0], xv, c0);
                c1 = mfma16(wC[(kt+4)*2+1], xv, c1);
            }
            BAR();

            // ---- I2: idle (G0 computes B) ----
            BAR();

            // ---- I3: C's hc-part -> tn = tanh(C) ----
            #pragma unroll
            for (int kt = 0; kt < 4; ++kt){
                bf16x8 hv = *(const bf16x8*)(hc_rd + kt*64);
                c0 = mfma16(wC[kt*2+0], hv, c0);
                c1 = mfma16(wC[kt*2+1], hv, c1);
            }
            *(bf16x4*)(tn_wr +  0) = tanh4(c0);
            *(bf16x4*)(tn_wr + 32) = tanh4(c1);
            BAR();

            // ---- I4: D = tn @ ns_w2 + b; EMA with register-carried state ----
            float4 u0 = *(const float4*)&u_lds[lc][uC];
            float4 u1 = *(const float4*)&u_lds[lc][uC + 16];
            f32x4 d0 = bD[0], d1 = bD[1];
            #pragma unroll
            for (int kt = 0; kt < 4; ++kt){
                bf16x8 tv = *(const bf16x8*)(tn_rd + kt*64);
                d0 = mfma16(wD[kt*2+0], tv, d0);
                d1 = mfma16(wD[kt*2+1], tv, d1);
            }
            if (STD){
                d0[0] = fabsf(d0[0]); d0[1] = fabsf(d0[1]);
                d0[2] = fabsf(d0[2]); d0[3] = fabsf(d0[3]);
                d1[0] = fabsf(d1[0]); d1[1] = fabsf(d1[1]);
                d1[2] = fabsf(d1[2]); d1[3] = fabsf(d1[3]);
            }
            old0[0] = fmaf(u0.x, old0[0] - d0[0], d0[0]);
            old0[1] = fmaf(u0.y, old0[1] - d0[1], d0[1]);
            old0[2] = fmaf(u0.z, old0[2] - d0[2], d0[2]);
            old0[3] = fmaf(u0.w, old0[3] - d0[3], d0[3]);
            old1[0] = fmaf(u1.x, old1[0] - d1[0], d1[0]);
            old1[1] = fmaf(u1.y, old1[1] - d1[1], d1[1]);
            old1[2] = fmaf(u1.z, old1[2] - d1[2], d1[2]);
            old1[3] = fmaf(u1.w, old1[3] - d1[3], d1[3]);
            *(float4*)&ys_lds[lc][fD]      = make_float4(old0[0], old0[1], old0[2], old0[3]);
            *(float4*)&ys_lds[lc][fD + 16] = make_float4(old1[0], old1[1], old1[2], old1[3]);
            bf16x4 hn0 = { (bf16)old0[0], (bf16)old0[1], (bf16)old0[2], (bf16)old0[3] };
            bf16x4 hn1 = { (bf16)old1[0], (bf16)old1[1], (bf16)old1[2], (bf16)old1[3] };
            *(bf16x4*)(hy_wr +  0) = hn0;
            *(bf16x4*)(hy_wr + 32) = hn1;
            BAR();
        }
    }

    // output: yT (4096x64) then sT (4096x64), fp32
    {
        int orow = tid >> 5;
        int ocol = (tid & 31) << 2;
        float4 v = *(const float4*)&ys_lds[orow][ocol];
        size_t gr = (size_t)(row0 + orow);
        if (ocol < 64) *(float4*)&out[gr*64 + ocol] = v;
        else           *(float4*)&out[(size_t)NB*64 + gr*64 + (ocol - 64)] = v;
    }
}

extern "C" void kernel_launch(void* const* d_in, const int* in_sizes, int n_in,
                              void* d_out, int out_size, void* d_ws, size_t ws_size,
                              hipStream_t stream) {
    const float* data  = (const float*)d_in[0];
    // d_in[1] = time_steps — unused by the reference computation
    const float* ug_w1 = (const float*)d_in[2];
    const float* ug_b1 = (const float*)d_in[3];
    const float* ug_w2 = (const float*)d_in[4];
    const float* ug_b2 = (const float*)d_in[5];
    const float* rg_w1 = (const float*)d_in[6];
    const float* rg_b1 = (const float*)d_in[7];
    const float* rg_w2 = (const float*)d_in[8];
    const float* rg_b2 = (const float*)d_in[9];
    const float* ns_w1 = (const float*)d_in[10];
    const float* ns_b1 = (const float*)d_in[11];
    const float* ns_w2 = (const float*)d_in[12];
    const float* ns_b2 = (const float*)d_in[13];

    hipLaunchKernelGGL(vae_rnn, dim3(NB/16), dim3(512), 0, stream,
                       data, ug_w1, ug_b1, ug_w2, ug_b2,
                       rg_w1, rg_b1, rg_w2, rg_b2,
                       ns_w1, ns_b1, ns_w2, ns_b2,
                       (float*)d_out);
}